// Round 7
// baseline (428.225 us; speedup 1.0000x reference)
//
#include <hip/hip_runtime.h>
#include <hip/hip_bf16.h>
#include <hip/hip_cooperative_groups.h>
#include <math.h>

namespace cg = cooperative_groups;

#define N_NODES 50000
#define N_EDGES 640000
#define DIM     128
#define NGRAPH  64
#define DOUT    32
#define POOL_CHUNK 32
#define PRE_BLOCKS 512                       // parallelism for atomic phases (R6 lesson: 98 was 8% occupancy)
#define PRE_THREADS 512
#define PRE_TOTAL (PRE_BLOCKS * PRE_THREADS)
#define SCAN_BLOCKS 98                       // ceil(50000/512): blocks that own a scan chunk

typedef unsigned short u16;
typedef __attribute__((ext_vector_type(8))) short bf16x8;
typedef __attribute__((ext_vector_type(4))) float f32x4;

// fp32 -> bf16 round-to-nearest-even (scalar)
__device__ __forceinline__ u16 f2bf(float f) {
    unsigned u = __float_as_uint(f);
    return (u16)((u + 0x7FFFu + ((u >> 16) & 1u)) >> 16);
}
__device__ __forceinline__ float bf2f(u16 h) {
    return __uint_as_float(((unsigned)h) << 16);
}
// packed fp32x2 -> bf16x2 RNE
__device__ __forceinline__ short2 cvt2(float x, float y) {
    __hip_bfloat162 h = __float22bfloat162_rn(make_float2(x, y));
    return *(short2*)&h;
}

// ================= fused preprocessing (cooperative, 1 launch, 512 blocks) =================
// count_deg -> grid.sync -> block scan (blocks 0..97) -> grid.sync -> finalize -> grid.sync -> fill
// + W1/W2 bf16 swizzle into MFMA B-frag order in phase 0.
__global__ __launch_bounds__(512) void k_pre(const int* __restrict__ src,
                                             const int* __restrict__ dst,
                                             int* __restrict__ deg,
                                             int* __restrict__ row_start,
                                             int* __restrict__ cursor,
                                             float* __restrict__ dinv,
                                             int* __restrict__ csr_src,
                                             int* __restrict__ bsum,
                                             const float* __restrict__ W1,
                                             const float* __restrict__ W2,
                                             u16* __restrict__ W1s,
                                             u16* __restrict__ W2s) {
    cg::grid_group grid = cg::this_grid();
    __shared__ int sd[512];
    __shared__ int sb[128];
    int t  = threadIdx.x;
    int gt = blockIdx.x * PRE_THREADS + t;

    // phase 0a: swizzle both weight matrices (2 x 16384 elems)
    if (gt < 32768) {
        int r = gt & 16383;
        int j = r & 7, lane = (r >> 3) & 63, kc = (r >> 9) & 3, nt = r >> 11;
        int k = kc * 32 + (lane >> 4) * 8 + j;
        int n = nt * 16 + (lane & 15);
        if (gt < 16384) W1s[r] = f2bf(W1[k * 128 + n]);
        else            W2s[r] = f2bf(W2[k * 128 + n]);
    }
    // phase 0b: in-degree count (deg zeroed by host-side memsetAsync); ~2.4 edges/thread
    for (int e = gt; e < N_EDGES; e += PRE_TOTAL) atomicAdd(&deg[dst[e]], 1);
    grid.sync();

    // phase 1: block-local exclusive scan of deg (512 nodes/chunk, blocks 0..97 only)
    if (blockIdx.x < SCAN_BLOCKS) {
        int i = gt;
        int v = (i < N_NODES) ? deg[i] : 0;
        int sum = v;
        sd[t] = v; __syncthreads();
        for (int off = 1; off < 512; off <<= 1) {
            int o = (t >= off) ? sd[t - off] : 0;
            __syncthreads();
            sum += o; sd[t] = sum;
            __syncthreads();
        }
        if (i < N_NODES) row_start[i] = sum - v;
        if (t == 511) bsum[blockIdx.x] = sum;
    }
    grid.sync();

    // phase 2: finalize -- in-LDS scan of 98 block sums, apply, cursor, dinv (blocks 0..97)
    if (blockIdx.x < SCAN_BLOCKS) {
        if (t < 128) sb[t] = (t < SCAN_BLOCKS) ? bsum[t] : 0;
        __syncthreads();
        for (int off = 1; off < 128; off <<= 1) {
            int vv = 0;
            if (t < 128 && t >= off) vv = sb[t - off];
            __syncthreads();
            if (t < 128) sb[t] += vv;
            __syncthreads();
        }
        int i = gt;
        if (i < N_NODES) {
            int b9 = i >> 9;
            int boff = (b9 == 0) ? 0 : sb[b9 - 1];
            int r = row_start[i] + boff;
            row_start[i] = r;
            cursor[i]    = r;
            dinv[i]      = rsqrtf((float)(deg[i] + 1));
        } else if (i == N_NODES) {
            row_start[N_NODES] = N_EDGES;
        }
    }
    grid.sync();

    // phase 3: CSR fill (4B src only; norm factored out, self-loops analytic)
    for (int e = gt; e < N_EDGES; e += PRE_TOTAL) {
        int pos = atomicAdd(&cursor[dst[e]], 1);
        csr_src[pos] = src[e];
    }
}

// ---------- fallback separate preprocessing (captured only if coop launch fails) ----------
__global__ __launch_bounds__(256) void k_count_deg(const int* __restrict__ dst, int* __restrict__ deg) {
    int e = blockIdx.x * 256 + threadIdx.x;
    if (e < N_EDGES) atomicAdd(&deg[dst[e]], 1);
}
__global__ __launch_bounds__(512) void k_scan_block(const int* __restrict__ deg,
                                                    int* __restrict__ row_start,
                                                    int* __restrict__ bsum) {
    __shared__ int sd[512];
    int t = threadIdx.x;
    int i = blockIdx.x * 512 + t;
    int v = (i < N_NODES) ? deg[i] : 0;
    int sum = v;
    sd[t] = v; __syncthreads();
    for (int off = 1; off < 512; off <<= 1) {
        int o = (t >= off) ? sd[t - off] : 0;
        __syncthreads();
        sum += o; sd[t] = sum;
        __syncthreads();
    }
    if (i < N_NODES) row_start[i] = sum - v;
    if (t == 511) bsum[blockIdx.x] = sum;
}
__global__ __launch_bounds__(256) void k_finalize(const int* __restrict__ deg,
                                                  const int* __restrict__ bsum,
                                                  int* __restrict__ row_start,
                                                  int* __restrict__ cursor,
                                                  float* __restrict__ dinv) {
    __shared__ int sb[128];
    int t = threadIdx.x;
    if (t < 128) sb[t] = (t < SCAN_BLOCKS) ? bsum[t] : 0;
    __syncthreads();
    for (int off = 1; off < 128; off <<= 1) {
        int v = 0;
        if (t < 128 && t >= off) v = sb[t - off];
        __syncthreads();
        if (t < 128) sb[t] += v;
        __syncthreads();
    }
    int i = blockIdx.x * 256 + t;
    if (i < N_NODES) {
        int b9 = i >> 9;
        int boff = (b9 == 0) ? 0 : sb[b9 - 1];
        int r = row_start[i] + boff;
        row_start[i] = r;
        cursor[i]    = r;
        dinv[i]      = rsqrtf((float)(deg[i] + 1));
    } else if (i == N_NODES) {
        row_start[N_NODES] = N_EDGES;
    }
}
__global__ __launch_bounds__(256) void k_fill(const int* __restrict__ src, const int* __restrict__ dst,
                                              int* __restrict__ cursor, int* __restrict__ csr_src) {
    int e = blockIdx.x * 256 + threadIdx.x;
    if (e < N_EDGES) {
        int pos = atomicAdd(&cursor[dst[e]], 1);
        csr_src[pos] = src[e];
    }
}
__global__ __launch_bounds__(256) void k_cvtW(const float* __restrict__ W, u16* __restrict__ Ws) {
    int t = blockIdx.x * 256 + threadIdx.x;
    int j = t & 7, lane = (t >> 3) & 63, kc = (t >> 9) & 3, nt = t >> 11;
    int k = kc * 32 + (lane >> 4) * 8 + j;
    int n = nt * 16 + (lane & 15);
    Ws[t] = f2bf(W[k * 128 + n]);
}

// ================= MFMA GEMM: Y(bf16) = dinv[row] * (A @ W) =================
// A frag: A[m=lane&15][k=(lane>>4)*8+j]; C/D: col=lane&15, row=(lane>>4)*4+reg. [verified R5/R6]
template <bool AF32>
__global__ __launch_bounds__(256) void k_gemm(const void* __restrict__ Av,
                                              const u16* __restrict__ Ws,
                                              const float* __restrict__ dinv,
                                              u16* __restrict__ Y) {
    int wv   = threadIdx.x >> 6;
    int lane = threadIdx.x & 63;
    int row0 = blockIdx.x * 64 + wv * 16;
    int m    = lane & 15;
    int quad = lane >> 4;
    int ar = min(row0 + m, N_NODES - 1);
    bf16x8 a[4];
    if (AF32) {
        const float* Arow = (const float*)Av + (size_t)ar * DIM;
#pragma unroll
        for (int kc = 0; kc < 4; ++kc) {
            const float4* p4 = (const float4*)(Arow + kc * 32 + quad * 8);
            float4 p = p4[0], q = p4[1];
            short2 s0 = cvt2(p.x, p.y), s1 = cvt2(p.z, p.w);
            short2 s2 = cvt2(q.x, q.y), s3 = cvt2(q.z, q.w);
            bf16x8 av;
            av[0] = s0.x; av[1] = s0.y; av[2] = s1.x; av[3] = s1.y;
            av[4] = s2.x; av[5] = s2.y; av[6] = s3.x; av[7] = s3.y;
            a[kc] = av;
        }
    } else {
        const u16* Arow = (const u16*)Av + (size_t)ar * DIM;
#pragma unroll
        for (int kc = 0; kc < 4; ++kc)
            a[kc] = *(const bf16x8*)(Arow + kc * 32 + quad * 8);
    }
    float di[4];
#pragma unroll
    for (int r = 0; r < 4; ++r) {
        int rr = row0 + quad * 4 + r;
        di[r] = (rr < N_NODES) ? dinv[rr] : 0.f;
    }
#pragma unroll
    for (int nt = 0; nt < 8; ++nt) {
        f32x4 acc = {0.f, 0.f, 0.f, 0.f};
#pragma unroll
        for (int kc = 0; kc < 4; ++kc) {
            bf16x8 b = *(const bf16x8*)(Ws + ((size_t)(nt * 4 + kc) * 64 + lane) * 8);
            acc = __builtin_amdgcn_mfma_f32_16x16x32_bf16(a[kc], b, acc, 0, 0, 0);
        }
        int col = nt * 16 + m;
#pragma unroll
        for (int r = 0; r < 4; ++r) {
            int rr = row0 + quad * 4 + r;
            if (rr < N_NODES) Y[(size_t)rr * DIM + col] = f2bf(acc[r] * di[r]);
        }
    }
}

// ================= gather-aggregate =================
// out_i = relu(dinv_i*(sum_{in(i)} hs_j + hs_i) + b), hs = dinv*h from GEMM epilogue.
// Half-wave (32 lanes x ushort4) per node, 8-deep unroll -> 16 row-loads in flight.
__global__ __launch_bounds__(256) void k_agg(const u16* __restrict__ H,
                                             const int* __restrict__ csr_src,
                                             const int* __restrict__ row_start,
                                             const float* __restrict__ dinv,
                                             const float* __restrict__ bias,
                                             u16* __restrict__ Out) {
    int node = blockIdx.x * 8 + (threadIdx.x >> 5);
    int lane = threadIdx.x & 31;
    if (node >= N_NODES) return;
    int e0 = row_start[node], e1 = row_start[node + 1];
    const ushort4* H4 = (const ushort4*)H;
    ushort4 sv = H4[(size_t)node * 32 + lane];
    float4 ac0 = make_float4(bf2f(sv.x), bf2f(sv.y), bf2f(sv.z), bf2f(sv.w));
    float4 ac1 = {0,0,0,0}, ac2 = {0,0,0,0}, ac3 = {0,0,0,0};
    for (int e = e0; e < e1; e += 8) {
        int   idx[8];
        float w[8];
        ushort4 v[8];
#pragma unroll
        for (int u = 0; u < 8; ++u) {
            int eu = e + u;
            int ec = min(eu, e1 - 1);
            idx[u] = csr_src[ec];
            w[u]   = (eu < e1) ? 1.f : 0.f;
        }
#pragma unroll
        for (int u = 0; u < 8; ++u) v[u] = H4[(size_t)idx[u] * 32 + lane];
#pragma unroll
        for (int u = 0; u < 8; ++u) {
            float4* a = (u & 3) == 0 ? &ac0 : (u & 3) == 1 ? &ac1 : (u & 3) == 2 ? &ac2 : &ac3;
            a->x = fmaf(w[u], bf2f(v[u].x), a->x);
            a->y = fmaf(w[u], bf2f(v[u].y), a->y);
            a->z = fmaf(w[u], bf2f(v[u].z), a->z);
            a->w = fmaf(w[u], bf2f(v[u].w), a->w);
        }
    }
    float di = dinv[node];
    float4 b = ((const float4*)bias)[lane];
    ushort4 o;
    o.x = f2bf(fmaxf(di * (ac0.x + ac1.x + ac2.x + ac3.x) + b.x, 0.f));
    o.y = f2bf(fmaxf(di * (ac0.y + ac1.y + ac2.y + ac3.y) + b.y, 0.f));
    o.z = f2bf(fmaxf(di * (ac0.z + ac1.z + ac2.z + ac3.z) + b.z, 0.f));
    o.w = f2bf(fmaxf(di * (ac0.w + ac1.w + ac2.w + ac3.w) + b.w, 0.f));
    ((ushort4*)Out)[(size_t)node * 32 + lane] = o;
}

// ---- global add pool over sorted batch: register run-length + atomic flush ----
// (R2 lesson: never per-lane atomics into 8K hot addresses -- 300us.)
__global__ __launch_bounds__(128) void k_pool(const u16* __restrict__ H,
                                              const int* __restrict__ batch,
                                              float* __restrict__ pooled) {
    int dim   = threadIdx.x;
    int start = blockIdx.x * POOL_CHUNK;
    if (start >= N_NODES) return;
    int end = min(start + POOL_CHUNK, N_NODES);
    float acc = 0.f;
    int cb = batch[start];
    for (int i = start; i < end; ++i) {
        int b = batch[i];
        if (b != cb) {
            atomicAdd(&pooled[cb * DIM + dim], acc);
            acc = 0.f; cb = b;
        }
        acc += bf2f(H[(size_t)i * DIM + dim]);
    }
    atomicAdd(&pooled[cb * DIM + dim], acc);
}

// ---- head: logits = pooled @ Wh + bh ; log_softmax per graph ----
__global__ __launch_bounds__(64) void k_head(const float* __restrict__ pooled,
                                             const float* __restrict__ Wh,
                                             const float* __restrict__ bh,
                                             float* __restrict__ out) {
    int g = blockIdx.x;
    int lane = threadIdx.x;
    int c = lane & 31;
    const float* p = pooled + g * DIM;
    float lg = bh[c];
#pragma unroll 8
    for (int k = 0; k < DIM; ++k) lg = fmaf(p[k], Wh[k * DOUT + c], lg);
    float m = lg;
    for (int off = 16; off >= 1; off >>= 1) m = fmaxf(m, __shfl_xor(m, off, 32));
    float ex = expf(lg - m);
    float s = ex;
    for (int off = 16; off >= 1; off >>= 1) s += __shfl_xor(s, off, 32);
    if (lane < 32) out[g * DOUT + c] = lg - m - logf(s);
}

extern "C" void kernel_launch(void* const* d_in, const int* in_sizes, int n_in,
                              void* d_out, int out_size, void* d_ws, size_t ws_size,
                              hipStream_t stream) {
    const float* x     = (const float*)d_in[0];
    const int*   ei    = (const int*)d_in[1];
    const int*   batch = (const int*)d_in[2];
    const float* W1    = (const float*)d_in[3];
    const float* b1    = (const float*)d_in[4];
    const float* W2    = (const float*)d_in[5];
    const float* b2    = (const float*)d_in[6];
    const float* Wh    = (const float*)d_in[7];
    const float* bh    = (const float*)d_in[8];
    float* out = (float*)d_out;
    const int* src = ei;
    const int* dst = ei + N_EDGES;

    char* ws = (char*)d_ws;
    size_t off = 0;
    auto alloc = [&](size_t bytes) {
        void* p = ws + off;
        off += (bytes + 255) & ~(size_t)255;
        return p;
    };
    u16*   bufA      = (u16*)  alloc((size_t)N_NODES * DIM * 2);   // 12.8 MB bf16
    u16*   bufB      = (u16*)  alloc((size_t)N_NODES * DIM * 2);   // 12.8 MB bf16
    float* pooled    = (float*)alloc((size_t)NGRAPH * DIM * 4);    // 32768 B (256-mult)
    int*   deg       = (int*)  alloc((size_t)N_NODES * 4);         // contiguous after pooled
    float* dinv      = (float*)alloc((size_t)N_NODES * 4);
    int*   row_start = (int*)  alloc((size_t)(N_NODES + 1) * 4);
    int*   cursor    = (int*)  alloc((size_t)N_NODES * 4);
    int*   csr_src   = (int*)  alloc((size_t)N_EDGES * 4);
    u16*   W1s       = (u16*)  alloc((size_t)DIM * DIM * 2);
    u16*   W2s       = (u16*)  alloc((size_t)DIM * DIM * 2);
    int*   bsum      = (int*)  alloc(128 * 4);
    (void)ws_size; (void)in_sizes; (void)n_in; (void)out_size;

    // one memset: pooled (32768 B) + deg (200000 B) are adjacent
    hipMemsetAsync(pooled, 0, 32768 + (size_t)N_NODES * 4, stream);

    void* pre_args[] = {(void*)&src, (void*)&dst, (void*)&deg, (void*)&row_start,
                        (void*)&cursor, (void*)&dinv, (void*)&csr_src, (void*)&bsum,
                        (void*)&W1, (void*)&W2, (void*)&W1s, (void*)&W2s};
    hipError_t cerr = hipLaunchCooperativeKernel((void*)k_pre, dim3(PRE_BLOCKS),
                                                 dim3(PRE_THREADS), pre_args, 0, stream);
    if (cerr != hipSuccess) {
        // deterministic fallback: proven R5 separate chain
        k_count_deg <<<(N_EDGES + 255) / 256, 256, 0, stream>>>(dst, deg);
        k_scan_block<<<SCAN_BLOCKS, 512, 0, stream>>>(deg, row_start, bsum);
        k_finalize  <<<(N_NODES + 256) / 256, 256, 0, stream>>>(deg, bsum, row_start, cursor, dinv);
        k_fill      <<<(N_EDGES + 255) / 256, 256, 0, stream>>>(src, dst, cursor, csr_src);
        k_cvtW      <<<64, 256, 0, stream>>>(W1, W1s);
        k_cvtW      <<<64, 256, 0, stream>>>(W2, W2s);
    }

    k_gemm<true> <<<(N_NODES + 63) / 64, 256, 0, stream>>>(x, W1s, dinv, bufA);
    k_agg        <<<(N_NODES + 7) / 8, 256, 0, stream>>>(bufA, csr_src, row_start, dinv, b1, bufB);
    k_gemm<false><<<(N_NODES + 63) / 64, 256, 0, stream>>>(bufB, W2s, dinv, bufA);
    k_agg        <<<(N_NODES + 7) / 8, 256, 0, stream>>>(bufA, csr_src, row_start, dinv, b2, bufB);

    k_pool<<<(N_NODES + POOL_CHUNK - 1) / POOL_CHUNK, 128, 0, stream>>>(bufB, batch, pooled);
    k_head<<<NGRAPH, 64, 0, stream>>>(pooled, Wh, bh, out);
}

// Round 8
// 251.943 us; speedup vs baseline: 1.6997x; 1.6997x over previous
//
#include <hip/hip_runtime.h>
#include <hip/hip_bf16.h>
#include <math.h>

#define N_NODES 50000
#define N_EDGES 640000
#define DIM     128
#define NGRAPH  64
#define DOUT    32
#define POOL_CHUNK 32
#define SCAN_BLOCKS 98

typedef unsigned short u16;
typedef __attribute__((ext_vector_type(8))) short bf16x8;
typedef __attribute__((ext_vector_type(4))) float f32x4;

// fp32 -> bf16 round-to-nearest-even (scalar)
__device__ __forceinline__ u16 f2bf(float f) {
    unsigned u = __float_as_uint(f);
    return (u16)((u + 0x7FFFu + ((u >> 16) & 1u)) >> 16);
}
__device__ __forceinline__ float bf2f(u16 h) {
    return __uint_as_float(((unsigned)h) << 16);
}
// packed fp32x2 -> bf16x2 RNE
__device__ __forceinline__ short2 cvt2(float x, float y) {
    __hip_bfloat162 h = __float22bfloat162_rn(make_float2(x, y));
    return *(short2*)&h;
}
// unpack 2 bf16 from one uint: lo = even dim, hi = odd dim (little-endian)
__device__ __forceinline__ void upk(unsigned u, float& lo, float& hi) {
    lo = __uint_as_float(u << 16);
    hi = __uint_as_float(u & 0xFFFF0000u);
}

// ======== preprocessing: separate kernels (R7 lesson: coop grid.sync costs ~70us/sync) ========
__global__ __launch_bounds__(256) void k_count_deg(const int* __restrict__ dst, int* __restrict__ deg) {
    int e = blockIdx.x * 256 + threadIdx.x;
    if (e < N_EDGES) atomicAdd(&deg[dst[e]], 1);
}

__global__ __launch_bounds__(512) void k_scan_block(const int* __restrict__ deg,
                                                    int* __restrict__ row_start,
                                                    int* __restrict__ bsum) {
    __shared__ int sd[512];
    int t = threadIdx.x;
    int i = blockIdx.x * 512 + t;
    int v = (i < N_NODES) ? deg[i] : 0;
    int sum = v;
    sd[t] = v; __syncthreads();
    for (int off = 1; off < 512; off <<= 1) {
        int o = (t >= off) ? sd[t - off] : 0;
        __syncthreads();
        sum += o; sd[t] = sum;
        __syncthreads();
    }
    if (i < N_NODES) row_start[i] = sum - v;
    if (t == 511) bsum[blockIdx.x] = sum;
}

__global__ __launch_bounds__(256) void k_finalize(const int* __restrict__ deg,
                                                  const int* __restrict__ bsum,
                                                  int* __restrict__ row_start,
                                                  int* __restrict__ cursor,
                                                  float* __restrict__ dinv) {
    __shared__ int sb[128];
    int t = threadIdx.x;
    if (t < 128) sb[t] = (t < SCAN_BLOCKS) ? bsum[t] : 0;
    __syncthreads();
    for (int off = 1; off < 128; off <<= 1) {
        int v = 0;
        if (t < 128 && t >= off) v = sb[t - off];
        __syncthreads();
        if (t < 128) sb[t] += v;
        __syncthreads();
    }
    int i = blockIdx.x * 256 + t;
    if (i < N_NODES) {
        int b9 = i >> 9;
        int boff = (b9 == 0) ? 0 : sb[b9 - 1];
        int r = row_start[i] + boff;
        row_start[i] = r;
        cursor[i]    = r;
        dinv[i]      = rsqrtf((float)(deg[i] + 1));
    } else if (i == N_NODES) {
        row_start[N_NODES] = N_EDGES;
    }
}

__global__ __launch_bounds__(256) void k_fill(const int* __restrict__ src, const int* __restrict__ dst,
                                              int* __restrict__ cursor, int* __restrict__ csr_src) {
    int e = blockIdx.x * 256 + threadIdx.x;
    if (e < N_EDGES) {
        int pos = atomicAdd(&cursor[dst[e]], 1);
        csr_src[pos] = src[e];
    }
}

// W -> bf16, pre-swizzled into MFMA B-fragment order (verified R5/R6)
__global__ __launch_bounds__(256) void k_cvtW(const float* __restrict__ W, u16* __restrict__ Ws) {
    int t = blockIdx.x * 256 + threadIdx.x;
    int j = t & 7, lane = (t >> 3) & 63, kc = (t >> 9) & 3, nt = t >> 11;
    int k = kc * 32 + (lane >> 4) * 8 + j;
    int n = nt * 16 + (lane & 15);
    Ws[t] = f2bf(W[k * 128 + n]);
}

// ================= MFMA GEMM: Y(bf16) = dinv[row] * (A @ W) =================
// A frag: A[m=lane&15][k=(lane>>4)*8+j]; C/D: col=lane&15, row=(lane>>4)*4+reg. [verified R5/R6]
template <bool AF32>
__global__ __launch_bounds__(256) void k_gemm(const void* __restrict__ Av,
                                              const u16* __restrict__ Ws,
                                              const float* __restrict__ dinv,
                                              u16* __restrict__ Y) {
    int wv   = threadIdx.x >> 6;
    int lane = threadIdx.x & 63;
    int row0 = blockIdx.x * 64 + wv * 16;
    int m    = lane & 15;
    int quad = lane >> 4;
    int ar = min(row0 + m, N_NODES - 1);
    bf16x8 a[4];
    if (AF32) {
        const float* Arow = (const float*)Av + (size_t)ar * DIM;
#pragma unroll
        for (int kc = 0; kc < 4; ++kc) {
            const float4* p4 = (const float4*)(Arow + kc * 32 + quad * 8);
            float4 p = p4[0], q = p4[1];
            short2 s0 = cvt2(p.x, p.y), s1 = cvt2(p.z, p.w);
            short2 s2 = cvt2(q.x, q.y), s3 = cvt2(q.z, q.w);
            bf16x8 av;
            av[0] = s0.x; av[1] = s0.y; av[2] = s1.x; av[3] = s1.y;
            av[4] = s2.x; av[5] = s2.y; av[6] = s3.x; av[7] = s3.y;
            a[kc] = av;
        }
    } else {
        const u16* Arow = (const u16*)Av + (size_t)ar * DIM;
#pragma unroll
        for (int kc = 0; kc < 4; ++kc)
            a[kc] = *(const bf16x8*)(Arow + kc * 32 + quad * 8);
    }
    float di[4];
#pragma unroll
    for (int r = 0; r < 4; ++r) {
        int rr = row0 + quad * 4 + r;
        di[r] = (rr < N_NODES) ? dinv[rr] : 0.f;
    }
#pragma unroll
    for (int nt = 0; nt < 8; ++nt) {
        f32x4 acc = {0.f, 0.f, 0.f, 0.f};
#pragma unroll
        for (int kc = 0; kc < 4; ++kc) {
            bf16x8 b = *(const bf16x8*)(Ws + ((size_t)(nt * 4 + kc) * 64 + lane) * 8);
            acc = __builtin_amdgcn_mfma_f32_16x16x32_bf16(a[kc], b, acc, 0, 0, 0);
        }
        int col = nt * 16 + m;
#pragma unroll
        for (int r = 0; r < 4; ++r) {
            int rr = row0 + quad * 4 + r;
            if (rr < N_NODES) Y[(size_t)rr * DIM + col] = f2bf(acc[r] * di[r]);
        }
    }
}

// ================= gather-aggregate =================
// out_i = relu(dinv_i*(sum_{in(i)} hs_j + hs_i) + b), hs = dinv*h (from GEMM epilogue).
// Quarter-wave layout: 16 lanes x uint4 (8 bf16 = 16B) per node. 8-deep unroll ->
// 32 independent rows in flight per wave (2x R5's half-wave/8B scheme), half the
// dynamic load instructions. bf16 unpack is shift/mask reinterpret (no cvt).
__global__ __launch_bounds__(256) void k_agg(const u16* __restrict__ H,
                                             const int* __restrict__ csr_src,
                                             const int* __restrict__ row_start,
                                             const float* __restrict__ dinv,
                                             const float* __restrict__ bias,
                                             u16* __restrict__ Out) {
    int node = blockIdx.x * 16 + (threadIdx.x >> 4);
    int lane = threadIdx.x & 15;                    // owns dims lane*8 .. lane*8+7
    if (node >= N_NODES) return;
    int e0 = row_start[node], e1 = row_start[node + 1];
    const uint4* H4 = (const uint4*)H;              // row = 16 uint4

    uint4 sv = H4[(size_t)node * 16 + lane];        // self term hs_i
    float a0[8], a1[8] = {}, a2[8] = {}, a3[8] = {};
    upk(sv.x, a0[0], a0[1]); upk(sv.y, a0[2], a0[3]);
    upk(sv.z, a0[4], a0[5]); upk(sv.w, a0[6], a0[7]);

    for (int e = e0; e < e1; e += 8) {
        int   idx[8];
        float w[8];
        uint4 v[8];
#pragma unroll
        for (int u = 0; u < 8; ++u) {
            int eu = e + u;
            int ec = min(eu, e1 - 1);
            idx[u] = csr_src[ec];
            w[u]   = (eu < e1) ? 1.f : 0.f;
        }
#pragma unroll
        for (int u = 0; u < 8; ++u) v[u] = H4[(size_t)idx[u] * 16 + lane];
#pragma unroll
        for (int u = 0; u < 8; ++u) {
            float* a = (u & 3) == 0 ? a0 : (u & 3) == 1 ? a1 : (u & 3) == 2 ? a2 : a3;
            float lo, hi;
            upk(v[u].x, lo, hi); a[0] = fmaf(w[u], lo, a[0]); a[1] = fmaf(w[u], hi, a[1]);
            upk(v[u].y, lo, hi); a[2] = fmaf(w[u], lo, a[2]); a[3] = fmaf(w[u], hi, a[3]);
            upk(v[u].z, lo, hi); a[4] = fmaf(w[u], lo, a[4]); a[5] = fmaf(w[u], hi, a[5]);
            upk(v[u].w, lo, hi); a[6] = fmaf(w[u], lo, a[6]); a[7] = fmaf(w[u], hi, a[7]);
        }
    }
    float di = dinv[node];
    const float4* b4 = (const float4*)bias;
    float4 blo = b4[lane * 2], bhi = b4[lane * 2 + 1];
    float r0 = fmaxf(di * (a0[0] + a1[0] + a2[0] + a3[0]) + blo.x, 0.f);
    float r1 = fmaxf(di * (a0[1] + a1[1] + a2[1] + a3[1]) + blo.y, 0.f);
    float r2 = fmaxf(di * (a0[2] + a1[2] + a2[2] + a3[2]) + blo.z, 0.f);
    float r3 = fmaxf(di * (a0[3] + a1[3] + a2[3] + a3[3]) + blo.w, 0.f);
    float r4 = fmaxf(di * (a0[4] + a1[4] + a2[4] + a3[4]) + bhi.x, 0.f);
    float r5 = fmaxf(di * (a0[5] + a1[5] + a2[5] + a3[5]) + bhi.y, 0.f);
    float r6 = fmaxf(di * (a0[6] + a1[6] + a2[6] + a3[6]) + bhi.z, 0.f);
    float r7 = fmaxf(di * (a0[7] + a1[7] + a2[7] + a3[7]) + bhi.w, 0.f);
    short2 s0 = cvt2(r0, r1), s1 = cvt2(r2, r3), s2 = cvt2(r4, r5), s3 = cvt2(r6, r7);
    uint4 o;
    o.x = *(unsigned*)&s0; o.y = *(unsigned*)&s1;
    o.z = *(unsigned*)&s2; o.w = *(unsigned*)&s3;
    ((uint4*)Out)[(size_t)node * 16 + lane] = o;
}

// ---- global add pool over sorted batch: register run-length + atomic flush ----
// (R2 lesson: never per-lane atomics into 8K hot addresses -- 300us.)
__global__ __launch_bounds__(128) void k_pool(const u16* __restrict__ H,
                                              const int* __restrict__ batch,
                                              float* __restrict__ pooled) {
    int dim   = threadIdx.x;
    int start = blockIdx.x * POOL_CHUNK;
    if (start >= N_NODES) return;
    int end = min(start + POOL_CHUNK, N_NODES);
    float acc = 0.f;
    int cb = batch[start];
    for (int i = start; i < end; ++i) {
        int b = batch[i];
        if (b != cb) {
            atomicAdd(&pooled[cb * DIM + dim], acc);
            acc = 0.f; cb = b;
        }
        acc += bf2f(H[(size_t)i * DIM + dim]);
    }
    atomicAdd(&pooled[cb * DIM + dim], acc);
}

// ---- head: logits = pooled @ Wh + bh ; log_softmax per graph ----
__global__ __launch_bounds__(64) void k_head(const float* __restrict__ pooled,
                                             const float* __restrict__ Wh,
                                             const float* __restrict__ bh,
                                             float* __restrict__ out) {
    int g = blockIdx.x;
    int lane = threadIdx.x;
    int c = lane & 31;
    const float* p = pooled + g * DIM;
    float lg = bh[c];
#pragma unroll 8
    for (int k = 0; k < DIM; ++k) lg = fmaf(p[k], Wh[k * DOUT + c], lg);
    float m = lg;
    for (int off = 16; off >= 1; off >>= 1) m = fmaxf(m, __shfl_xor(m, off, 32));
    float ex = expf(lg - m);
    float s = ex;
    for (int off = 16; off >= 1; off >>= 1) s += __shfl_xor(s, off, 32);
    if (lane < 32) out[g * DOUT + c] = lg - m - logf(s);
}

extern "C" void kernel_launch(void* const* d_in, const int* in_sizes, int n_in,
                              void* d_out, int out_size, void* d_ws, size_t ws_size,
                              hipStream_t stream) {
    const float* x     = (const float*)d_in[0];
    const int*   ei    = (const int*)d_in[1];
    const int*   batch = (const int*)d_in[2];
    const float* W1    = (const float*)d_in[3];
    const float* b1    = (const float*)d_in[4];
    const float* W2    = (const float*)d_in[5];
    const float* b2    = (const float*)d_in[6];
    const float* Wh    = (const float*)d_in[7];
    const float* bh    = (const float*)d_in[8];
    float* out = (float*)d_out;
    const int* src = ei;
    const int* dst = ei + N_EDGES;

    char* ws = (char*)d_ws;
    size_t off = 0;
    auto alloc = [&](size_t bytes) {
        void* p = ws + off;
        off += (bytes + 255) & ~(size_t)255;
        return p;
    };
    u16*   bufA      = (u16*)  alloc((size_t)N_NODES * DIM * 2);   // 12.8 MB bf16
    u16*   bufB      = (u16*)  alloc((size_t)N_NODES * DIM * 2);   // 12.8 MB bf16
    float* pooled    = (float*)alloc((size_t)NGRAPH * DIM * 4);    // 32768 B (256-mult)
    int*   deg       = (int*)  alloc((size_t)N_NODES * 4);         // contiguous after pooled
    float* dinv      = (float*)alloc((size_t)N_NODES * 4);
    int*   row_start = (int*)  alloc((size_t)(N_NODES + 1) * 4);
    int*   cursor    = (int*)  alloc((size_t)N_NODES * 4);
    int*   csr_src   = (int*)  alloc((size_t)N_EDGES * 4);
    u16*   W1s       = (u16*)  alloc((size_t)DIM * DIM * 2);
    u16*   W2s       = (u16*)  alloc((size_t)DIM * DIM * 2);
    int*   bsum      = (int*)  alloc(128 * 4);
    (void)ws_size; (void)in_sizes; (void)n_in; (void)out_size;

    // one memset: pooled (32768 B) + deg (200000 B) are adjacent
    hipMemsetAsync(pooled, 0, 32768 + (size_t)N_NODES * 4, stream);

    k_count_deg <<<(N_EDGES + 255) / 256, 256, 0, stream>>>(dst, deg);
    k_scan_block<<<SCAN_BLOCKS, 512, 0, stream>>>(deg, row_start, bsum);
    k_finalize  <<<(N_NODES + 256) / 256, 256, 0, stream>>>(deg, bsum, row_start, cursor, dinv);
    k_fill      <<<(N_EDGES + 255) / 256, 256, 0, stream>>>(src, dst, cursor, csr_src);
    k_cvtW      <<<64, 256, 0, stream>>>(W1, W1s);
    k_cvtW      <<<64, 256, 0, stream>>>(W2, W2s);

    k_gemm<true> <<<(N_NODES + 63) / 64, 256, 0, stream>>>(x, W1s, dinv, bufA);
    k_agg        <<<(N_NODES + 15) / 16, 256, 0, stream>>>(bufA, csr_src, row_start, dinv, b1, bufB);
    k_gemm<false><<<(N_NODES + 63) / 64, 256, 0, stream>>>(bufB, W2s, dinv, bufA);
    k_agg        <<<(N_NODES + 15) / 16, 256, 0, stream>>>(bufA, csr_src, row_start, dinv, b2, bufB);

    k_pool<<<(N_NODES + POOL_CHUNK - 1) / POOL_CHUNK, 128, 0, stream>>>(bufB, batch, pooled);
    k_head<<<NGRAPH, 64, 0, stream>>>(pooled, Wh, bh, out);
}

// Round 9
// 236.835 us; speedup vs baseline: 1.8081x; 1.0638x over previous
//
#include <hip/hip_runtime.h>
#include <hip/hip_bf16.h>
#include <math.h>

#define N_NODES 50000
#define N_EDGES 640000
#define DIM     128
#define NGRAPH  64
#define DOUT    32
#define POOL_CHUNK 32
#define SCAN_BLOCKS 98
#define CNT_BLOCKS 2500                 // N_EDGES/256
#define LDSS 136                        // 128 + 8 pad (u16): phase-B LDS reads 2-way (free)

typedef unsigned short u16;
typedef __attribute__((ext_vector_type(8))) short bf16x8;
typedef __attribute__((ext_vector_type(4))) float f32x4;

__device__ __forceinline__ u16 f2bf(float f) {
    unsigned u = __float_as_uint(f);
    return (u16)((u + 0x7FFFu + ((u >> 16) & 1u)) >> 16);
}
__device__ __forceinline__ float bf2f(u16 h) {
    return __uint_as_float(((unsigned)h) << 16);
}
__device__ __forceinline__ short2 cvt2(float x, float y) {
    __hip_bfloat162 h = __float22bfloat162_rn(make_float2(x, y));
    return *(short2*)&h;
}
__device__ __forceinline__ void upk(unsigned u, float& lo, float& hi) {
    lo = __uint_as_float(u << 16);
    hi = __uint_as_float(u & 0xFFFF0000u);
}

// ======== fused: degree count + W1/W2 swizzle-to-bf16 + pooled zero (independent jobs) ========
// B frag (16x16x32): lane holds B[k][n], n=lane&15, k=(lane>>4)*8+j  [verified R5-R8]
__global__ __launch_bounds__(256) void k_count_cvt(const int* __restrict__ dst, int* __restrict__ deg,
                                                   const float* __restrict__ W1, const float* __restrict__ W2,
                                                   u16* __restrict__ W1s, u16* __restrict__ W2s,
                                                   float* __restrict__ pooled) {
    int b = blockIdx.x;
    if (b < CNT_BLOCKS) {
        int e = b * 256 + threadIdx.x;
        if (e < N_EDGES) atomicAdd(&deg[dst[e]], 1);
    } else if (b < CNT_BLOCKS + 128) {
        int t = (b - CNT_BLOCKS) * 256 + threadIdx.x;   // 0..32767
        int r = t & 16383;
        int j = r & 7, lane = (r >> 3) & 63, kc = (r >> 9) & 3, nt = r >> 11;
        int k = kc * 32 + (lane >> 4) * 8 + j;
        int n = nt * 16 + (lane & 15);
        if (t < 16384) W1s[r] = f2bf(W1[k * 128 + n]);
        else           W2s[r] = f2bf(W2[k * 128 + n]);
    } else {
        int t = (b - CNT_BLOCKS - 128) * 256 + threadIdx.x;
        if (t < NGRAPH * DIM) pooled[t] = 0.f;
    }
}

// ======== preprocessing chain (R7 lesson: no cooperative grid.sync -- ~70us/sync) ========
__global__ __launch_bounds__(512) void k_scan_block(const int* __restrict__ deg,
                                                    int* __restrict__ row_start,
                                                    int* __restrict__ bsum) {
    __shared__ int sd[512];
    int t = threadIdx.x;
    int i = blockIdx.x * 512 + t;
    int v = (i < N_NODES) ? deg[i] : 0;
    int sum = v;
    sd[t] = v; __syncthreads();
    for (int off = 1; off < 512; off <<= 1) {
        int o = (t >= off) ? sd[t - off] : 0;
        __syncthreads();
        sum += o; sd[t] = sum;
        __syncthreads();
    }
    if (i < N_NODES) row_start[i] = sum - v;
    if (t == 511) bsum[blockIdx.x] = sum;
}

__global__ __launch_bounds__(256) void k_finalize(const int* __restrict__ deg,
                                                  const int* __restrict__ bsum,
                                                  int* __restrict__ row_start,
                                                  int* __restrict__ cursor,
                                                  float* __restrict__ dinv) {
    __shared__ int sb[128];
    int t = threadIdx.x;
    if (t < 128) sb[t] = (t < SCAN_BLOCKS) ? bsum[t] : 0;
    __syncthreads();
    for (int off = 1; off < 128; off <<= 1) {
        int v = 0;
        if (t < 128 && t >= off) v = sb[t - off];
        __syncthreads();
        if (t < 128) sb[t] += v;
        __syncthreads();
    }
    int i = blockIdx.x * 256 + t;
    if (i < N_NODES) {
        int b9 = i >> 9;
        int boff = (b9 == 0) ? 0 : sb[b9 - 1];
        int r = row_start[i] + boff;
        row_start[i] = r;
        cursor[i]    = r;
        dinv[i]      = rsqrtf((float)(deg[i] + 1));
    } else if (i == N_NODES) {
        row_start[N_NODES] = N_EDGES;
    }
}

__global__ __launch_bounds__(256) void k_fill(const int* __restrict__ src, const int* __restrict__ dst,
                                              int* __restrict__ cursor, int* __restrict__ csr_src) {
    int e = blockIdx.x * 256 + threadIdx.x;
    if (e < N_EDGES) {
        int pos = atomicAdd(&cursor[dst[e]], 1);
        csr_src[pos] = src[e];
    }
}

// ================= MFMA GEMM1: Y(bf16) = dinv[row] * (Xfp32 @ W1) =================
// A frag: A[m=lane&15][k=(lane>>4)*8+j]; C/D: col=lane&15, row=(lane>>4)*4+reg. [verified R5-R8]
__global__ __launch_bounds__(256) void k_gemm1(const float* __restrict__ X,
                                               const u16* __restrict__ Ws,
                                               const float* __restrict__ dinv,
                                               u16* __restrict__ Y) {
    int wv   = threadIdx.x >> 6;
    int lane = threadIdx.x & 63;
    int row0 = blockIdx.x * 64 + wv * 16;
    int m    = lane & 15;
    int quad = lane >> 4;
    int ar = min(row0 + m, N_NODES - 1);
    const float* Arow = X + (size_t)ar * DIM;
    bf16x8 a[4];
#pragma unroll
    for (int kc = 0; kc < 4; ++kc) {
        const float4* p4 = (const float4*)(Arow + kc * 32 + quad * 8);
        float4 p = p4[0], q = p4[1];
        short2 s0 = cvt2(p.x, p.y), s1 = cvt2(p.z, p.w);
        short2 s2 = cvt2(q.x, q.y), s3 = cvt2(q.z, q.w);
        bf16x8 av;
        av[0] = s0.x; av[1] = s0.y; av[2] = s1.x; av[3] = s1.y;
        av[4] = s2.x; av[5] = s2.y; av[6] = s3.x; av[7] = s3.y;
        a[kc] = av;
    }
    float di[4];
#pragma unroll
    for (int r = 0; r < 4; ++r) {
        int rr = row0 + quad * 4 + r;
        di[r] = (rr < N_NODES) ? dinv[rr] : 0.f;
    }
#pragma unroll
    for (int nt = 0; nt < 8; ++nt) {
        f32x4 acc = {0.f, 0.f, 0.f, 0.f};
#pragma unroll
        for (int kc = 0; kc < 4; ++kc) {
            bf16x8 b = *(const bf16x8*)(Ws + ((size_t)(nt * 4 + kc) * 64 + lane) * 8);
            acc = __builtin_amdgcn_mfma_f32_16x16x32_bf16(a[kc], b, acc, 0, 0, 0);
        }
        int col = nt * 16 + m;
#pragma unroll
        for (int r = 0; r < 4; ++r) {
            int rr = row0 + quad * 4 + r;
            if (rr < N_NODES) Y[(size_t)rr * DIM + col] = f2bf(acc[r] * di[r]);
        }
    }
}

// ================= fused agg1 + gemm2 =================
// Phase A (quarter-wave agg, 16 nodes/block): h1 = relu(dinv*(sum hs_j + hs_i) + b1) -> LDS tile.
// Phase B: hs2 = dinv * (h1 @ W2) via 16x16x32 MFMA, A-frags from the LDS tile.
// 50000 = 3125*16 exactly -> no row tail anywhere.
__global__ __launch_bounds__(256) void k_agg_gemm(const u16* __restrict__ H,
                                                  const int* __restrict__ csr_src,
                                                  const int* __restrict__ row_start,
                                                  const float* __restrict__ dinv,
                                                  const float* __restrict__ bias,
                                                  const u16* __restrict__ Ws,
                                                  u16* __restrict__ Y) {
    __shared__ u16 As[16][LDSS];
    int tid   = threadIdx.x;
    int nloc  = tid >> 4;
    int lane16 = tid & 15;
    int node  = blockIdx.x * 16 + nloc;

    // ---- phase A: aggregate (identical math to R8 k_agg) ----
    int e0 = row_start[node], e1 = row_start[node + 1];
    const uint4* H4 = (const uint4*)H;
    uint4 sv = H4[(size_t)node * 16 + lane16];
    float a0[8], a1[8] = {}, a2[8] = {}, a3[8] = {};
    upk(sv.x, a0[0], a0[1]); upk(sv.y, a0[2], a0[3]);
    upk(sv.z, a0[4], a0[5]); upk(sv.w, a0[6], a0[7]);
    for (int e = e0; e < e1; e += 8) {
        int   idx[8];
        float w[8];
        uint4 v[8];
#pragma unroll
        for (int u = 0; u < 8; ++u) {
            int eu = e + u;
            int ec = min(eu, e1 - 1);
            idx[u] = csr_src[ec];
            w[u]   = (eu < e1) ? 1.f : 0.f;
        }
#pragma unroll
        for (int u = 0; u < 8; ++u) v[u] = H4[(size_t)idx[u] * 16 + lane16];
#pragma unroll
        for (int u = 0; u < 8; ++u) {
            float* a = (u & 3) == 0 ? a0 : (u & 3) == 1 ? a1 : (u & 3) == 2 ? a2 : a3;
            float lo, hi;
            upk(v[u].x, lo, hi); a[0] = fmaf(w[u], lo, a[0]); a[1] = fmaf(w[u], hi, a[1]);
            upk(v[u].y, lo, hi); a[2] = fmaf(w[u], lo, a[2]); a[3] = fmaf(w[u], hi, a[3]);
            upk(v[u].z, lo, hi); a[4] = fmaf(w[u], lo, a[4]); a[5] = fmaf(w[u], hi, a[5]);
            upk(v[u].w, lo, hi); a[6] = fmaf(w[u], lo, a[6]); a[7] = fmaf(w[u], hi, a[7]);
        }
    }
    {
        float di = dinv[node];
        const float4* b4 = (const float4*)bias;
        float4 blo = b4[lane16 * 2], bhi = b4[lane16 * 2 + 1];
        float r0 = fmaxf(di * (a0[0] + a1[0] + a2[0] + a3[0]) + blo.x, 0.f);
        float r1 = fmaxf(di * (a0[1] + a1[1] + a2[1] + a3[1]) + blo.y, 0.f);
        float r2 = fmaxf(di * (a0[2] + a1[2] + a2[2] + a3[2]) + blo.z, 0.f);
        float r3 = fmaxf(di * (a0[3] + a1[3] + a2[3] + a3[3]) + blo.w, 0.f);
        float r4 = fmaxf(di * (a0[4] + a1[4] + a2[4] + a3[4]) + bhi.x, 0.f);
        float r5 = fmaxf(di * (a0[5] + a1[5] + a2[5] + a3[5]) + bhi.y, 0.f);
        float r6 = fmaxf(di * (a0[6] + a1[6] + a2[6] + a3[6]) + bhi.z, 0.f);
        float r7 = fmaxf(di * (a0[7] + a1[7] + a2[7] + a3[7]) + bhi.w, 0.f);
        short2 s0 = cvt2(r0, r1), s1 = cvt2(r2, r3), s2 = cvt2(r4, r5), s3 = cvt2(r6, r7);
        uint4 o;
        o.x = *(unsigned*)&s0; o.y = *(unsigned*)&s1;
        o.z = *(unsigned*)&s2; o.w = *(unsigned*)&s3;
        *(uint4*)(&As[nloc][lane16 * 8]) = o;       // row stride 272B (16B-aligned)
    }
    __syncthreads();

    // ---- phase B: 16x128 @ 128x128 MFMA; wave wv owns cols wv*32..wv*32+31 ----
    int wv   = tid >> 6;
    int lane = tid & 63;
    int m    = lane & 15;
    int quad = lane >> 4;
    bf16x8 a[4];
#pragma unroll
    for (int kc = 0; kc < 4; ++kc)
        a[kc] = *(const bf16x8*)(&As[m][kc * 32 + quad * 8]);
    float di[4];
#pragma unroll
    for (int r = 0; r < 4; ++r) di[r] = dinv[blockIdx.x * 16 + quad * 4 + r];
#pragma unroll
    for (int i = 0; i < 2; ++i) {
        int nt = wv * 2 + i;
        f32x4 acc = {0.f, 0.f, 0.f, 0.f};
#pragma unroll
        for (int kc = 0; kc < 4; ++kc) {
            bf16x8 b = *(const bf16x8*)(Ws + ((size_t)(nt * 4 + kc) * 64 + lane) * 8);
            acc = __builtin_amdgcn_mfma_f32_16x16x32_bf16(a[kc], b, acc, 0, 0, 0);
        }
        int col = nt * 16 + m;
#pragma unroll
        for (int r = 0; r < 4; ++r) {
            int rr = blockIdx.x * 16 + quad * 4 + r;
            Y[(size_t)rr * DIM + col] = f2bf(acc[r] * di[r]);
        }
    }
}

// ================= agg layer 2 (quarter-wave, unchanged from R8) =================
__global__ __launch_bounds__(256) void k_agg(const u16* __restrict__ H,
                                             const int* __restrict__ csr_src,
                                             const int* __restrict__ row_start,
                                             const float* __restrict__ dinv,
                                             const float* __restrict__ bias,
                                             u16* __restrict__ Out) {
    int node = blockIdx.x * 16 + (threadIdx.x >> 4);
    int lane = threadIdx.x & 15;
    if (node >= N_NODES) return;
    int e0 = row_start[node], e1 = row_start[node + 1];
    const uint4* H4 = (const uint4*)H;
    uint4 sv = H4[(size_t)node * 16 + lane];
    float a0[8], a1[8] = {}, a2[8] = {}, a3[8] = {};
    upk(sv.x, a0[0], a0[1]); upk(sv.y, a0[2], a0[3]);
    upk(sv.z, a0[4], a0[5]); upk(sv.w, a0[6], a0[7]);
    for (int e = e0; e < e1; e += 8) {
        int   idx[8];
        float w[8];
        uint4 v[8];
#pragma unroll
        for (int u = 0; u < 8; ++u) {
            int eu = e + u;
            int ec = min(eu, e1 - 1);
            idx[u] = csr_src[ec];
            w[u]   = (eu < e1) ? 1.f : 0.f;
        }
#pragma unroll
        for (int u = 0; u < 8; ++u) v[u] = H4[(size_t)idx[u] * 16 + lane];
#pragma unroll
        for (int u = 0; u < 8; ++u) {
            float* a = (u & 3) == 0 ? a0 : (u & 3) == 1 ? a1 : (u & 3) == 2 ? a2 : a3;
            float lo, hi;
            upk(v[u].x, lo, hi); a[0] = fmaf(w[u], lo, a[0]); a[1] = fmaf(w[u], hi, a[1]);
            upk(v[u].y, lo, hi); a[2] = fmaf(w[u], lo, a[2]); a[3] = fmaf(w[u], hi, a[3]);
            upk(v[u].z, lo, hi); a[4] = fmaf(w[u], lo, a[4]); a[5] = fmaf(w[u], hi, a[5]);
            upk(v[u].w, lo, hi); a[6] = fmaf(w[u], lo, a[6]); a[7] = fmaf(w[u], hi, a[7]);
        }
    }
    float di = dinv[node];
    const float4* b4 = (const float4*)bias;
    float4 blo = b4[lane * 2], bhi = b4[lane * 2 + 1];
    float r0 = fmaxf(di * (a0[0] + a1[0] + a2[0] + a3[0]) + blo.x, 0.f);
    float r1 = fmaxf(di * (a0[1] + a1[1] + a2[1] + a3[1]) + blo.y, 0.f);
    float r2 = fmaxf(di * (a0[2] + a1[2] + a2[2] + a3[2]) + blo.z, 0.f);
    float r3 = fmaxf(di * (a0[3] + a1[3] + a2[3] + a3[3]) + blo.w, 0.f);
    float r4 = fmaxf(di * (a0[4] + a1[4] + a2[4] + a3[4]) + bhi.x, 0.f);
    float r5 = fmaxf(di * (a0[5] + a1[5] + a2[5] + a3[5]) + bhi.y, 0.f);
    float r6 = fmaxf(di * (a0[6] + a1[6] + a2[6] + a3[6]) + bhi.z, 0.f);
    float r7 = fmaxf(di * (a0[7] + a1[7] + a2[7] + a3[7]) + bhi.w, 0.f);
    short2 s0 = cvt2(r0, r1), s1 = cvt2(r2, r3), s2 = cvt2(r4, r5), s3 = cvt2(r6, r7);
    uint4 o;
    o.x = *(unsigned*)&s0; o.y = *(unsigned*)&s1;
    o.z = *(unsigned*)&s2; o.w = *(unsigned*)&s3;
    ((uint4*)Out)[(size_t)node * 16 + lane] = o;
}

// ---- global add pool over sorted batch: register run-length + atomic flush ----
// (R2 lesson: never per-lane atomics into 8K hot addresses -- 300us.)
__global__ __launch_bounds__(128) void k_pool(const u16* __restrict__ H,
                                              const int* __restrict__ batch,
                                              float* __restrict__ pooled) {
    int dim   = threadIdx.x;
    int start = blockIdx.x * POOL_CHUNK;
    if (start >= N_NODES) return;
    int end = min(start + POOL_CHUNK, N_NODES);
    float acc = 0.f;
    int cb = batch[start];
    for (int i = start; i < end; ++i) {
        int b = batch[i];
        if (b != cb) {
            atomicAdd(&pooled[cb * DIM + dim], acc);
            acc = 0.f; cb = b;
        }
        acc += bf2f(H[(size_t)i * DIM + dim]);
    }
    atomicAdd(&pooled[cb * DIM + dim], acc);
}

// ---- head: logits = pooled @ Wh + bh ; log_softmax per graph ----
__global__ __launch_bounds__(64) void k_head(const float* __restrict__ pooled,
                                             const float* __restrict__ Wh,
                                             const float* __restrict__ bh,
                                             float* __restrict__ out) {
    int g = blockIdx.x;
    int lane = threadIdx.x;
    int c = lane & 31;
    const float* p = pooled + g * DIM;
    float lg = bh[c];
#pragma unroll 8
    for (int k = 0; k < DIM; ++k) lg = fmaf(p[k], Wh[k * DOUT + c], lg);
    float m = lg;
    for (int off = 16; off >= 1; off >>= 1) m = fmaxf(m, __shfl_xor(m, off, 32));
    float ex = expf(lg - m);
    float s = ex;
    for (int off = 16; off >= 1; off >>= 1) s += __shfl_xor(s, off, 32);
    if (lane < 32) out[g * DOUT + c] = lg - m - logf(s);
}

extern "C" void kernel_launch(void* const* d_in, const int* in_sizes, int n_in,
                              void* d_out, int out_size, void* d_ws, size_t ws_size,
                              hipStream_t stream) {
    const float* x     = (const float*)d_in[0];
    const int*   ei    = (const int*)d_in[1];
    const int*   batch = (const int*)d_in[2];
    const float* W1    = (const float*)d_in[3];
    const float* b1    = (const float*)d_in[4];
    const float* W2    = (const float*)d_in[5];
    const float* b2    = (const float*)d_in[6];
    const float* Wh    = (const float*)d_in[7];
    const float* bh    = (const float*)d_in[8];
    float* out = (float*)d_out;
    const int* src = ei;
    const int* dst = ei + N_EDGES;

    char* ws = (char*)d_ws;
    size_t off = 0;
    auto alloc = [&](size_t bytes) {
        void* p = ws + off;
        off += (bytes + 255) & ~(size_t)255;
        return p;
    };
    u16*   bufA      = (u16*)  alloc((size_t)N_NODES * DIM * 2);   // 12.8 MB bf16
    u16*   bufB      = (u16*)  alloc((size_t)N_NODES * DIM * 2);   // 12.8 MB bf16
    float* pooled    = (float*)alloc((size_t)NGRAPH * DIM * 4);
    int*   deg       = (int*)  alloc((size_t)N_NODES * 4);
    float* dinv      = (float*)alloc((size_t)N_NODES * 4);
    int*   row_start = (int*)  alloc((size_t)(N_NODES + 1) * 4);
    int*   cursor    = (int*)  alloc((size_t)N_NODES * 4);
    int*   csr_src   = (int*)  alloc((size_t)N_EDGES * 4);
    u16*   W1s       = (u16*)  alloc((size_t)DIM * DIM * 2);
    u16*   W2s       = (u16*)  alloc((size_t)DIM * DIM * 2);
    int*   bsum      = (int*)  alloc(128 * 4);
    (void)ws_size; (void)in_sizes; (void)n_in; (void)out_size;

    hipMemsetAsync(deg, 0, (size_t)N_NODES * 4, stream);

    k_count_cvt<<<CNT_BLOCKS + 128 + 32, 256, 0, stream>>>(dst, deg, W1, W2, W1s, W2s, pooled);
    k_scan_block<<<SCAN_BLOCKS, 512, 0, stream>>>(deg, row_start, bsum);
    k_finalize  <<<(N_NODES + 256) / 256, 256, 0, stream>>>(deg, bsum, row_start, cursor, dinv);
    k_fill      <<<CNT_BLOCKS, 256, 0, stream>>>(src, dst, cursor, csr_src);

    k_gemm1   <<<(N_NODES + 63) / 64, 256, 0, stream>>>(x, W1s, dinv, bufA);
    k_agg_gemm<<<N_NODES / 16, 256, 0, stream>>>(bufA, csr_src, row_start, dinv, b1, W2s, bufB);
    k_agg     <<<N_NODES / 16, 256, 0, stream>>>(bufB, csr_src, row_start, dinv, b2, bufA);

    k_pool<<<(N_NODES + POOL_CHUNK - 1) / POOL_CHUNK, 128, 0, stream>>>(bufA, batch, pooled);
    k_head<<<NGRAPH, 64, 0, stream>>>(pooled, Wh, bh, out);
}